// Round 1
// baseline (270.171 us; speedup 1.0000x reference)
//
#include <hip/hip_runtime.h>
#include <math.h>

// Problem constants
#define KS    11
#define HALO  (KS - 1)
#define H     512
#define W     512
#define OH    (H - HALO)   // 502
#define OW    (W - HALO)   // 502
#define NPLANES 48         // 16 * 3

// Tiling
#define TW 32
#define TH 32
#define IW (TW + HALO)     // 42
#define IH (TH + HALO)     // 42
#define LW (IW + 1)        // 43: pad -> row stride 43 = 11 mod 32 banks (<=2-way, free)

#define NTHREADS 256
#define TOTAL_OUT (NPLANES * OH * OW)   // 12,096,192

__global__ void zero_out_kernel(float* out) { out[0] = 0.0f; }

__global__ __launch_bounds__(NTHREADS) void ssim_kernel(
    const float* __restrict__ x,
    const float* __restrict__ y,
    const float* __restrict__ win,
    float* __restrict__ out)
{
    __shared__ float sx[IH][LW];
    __shared__ float sy[IH][LW];
    __shared__ float v[5][TH][LW];   // vertical-conv intermediates
    __shared__ float w1[KS];
    __shared__ float wsum[NTHREADS / 64];

    const int t  = threadIdx.x;
    const int x0 = blockIdx.x * TW;
    const int y0 = blockIdx.y * TH;
    const int plane = blockIdx.z;

    const float* __restrict__ xp = x + (size_t)plane * (H * W);
    const float* __restrict__ yp = y + (size_t)plane * (H * W);

    // Recover separable 1D taps: window = outer(g,g) => g[i] = sqrt(win[i][i])
    if (t < KS) w1[t] = sqrtf(win[t * KS + t]);

    // ---- Stage 1: global -> LDS input tiles (zero-fill out-of-range) ----
    for (int e = t; e < IH * IW; e += NTHREADS) {
        int r = e / IW, c = e % IW;
        int gy = y0 + r, gx = x0 + c;
        float vx = 0.0f, vy = 0.0f;
        if (gy < H && gx < W) {
            vx = xp[gy * W + gx];
            vy = yp[gy * W + gx];
        }
        sx[r][c] = vx;
        sy[r][c] = vy;
    }
    __syncthreads();

    // ---- Stage 2: vertical 11-tap conv, 5 signals ----
    for (int e = t; e < TH * IW; e += NTHREADS) {
        int r = e / IW, c = e % IW;
        float a0 = 0.f, a1 = 0.f, a2 = 0.f, a3 = 0.f, a4 = 0.f;
#pragma unroll
        for (int k = 0; k < KS; k++) {
            float wk = w1[k];
            float xv = sx[r + k][c];
            float yv = sy[r + k][c];
            a0 += wk * xv;
            a1 += wk * yv;
            a2 += wk * xv * xv;
            a3 += wk * yv * yv;
            a4 += wk * xv * yv;
        }
        v[0][r][c] = a0;
        v[1][r][c] = a1;
        v[2][r][c] = a2;
        v[3][r][c] = a3;
        v[4][r][c] = a4;
    }
    __syncthreads();

    // ---- Stage 3: horizontal 11-tap conv + SSIM + partial reduce ----
    const float c1 = 1e-4f;   // (0.01 * 1.0)^2
    const float c2 = 9e-4f;   // (0.03 * 1.0)^2
    float acc = 0.0f;
#pragma unroll
    for (int j = 0; j < (TW * TH) / NTHREADS; j++) {
        int o = t + NTHREADS * j;
        int r = o >> 5;        // / TW
        int c = o & 31;        // % TW
        if ((x0 + c) < OW && (y0 + r) < OH) {
            float m0 = 0.f, m1 = 0.f, m2 = 0.f, m3 = 0.f, m4 = 0.f;
#pragma unroll
            for (int k = 0; k < KS; k++) {
                float wk = w1[k];
                m0 += wk * v[0][r][c + k];
                m1 += wk * v[1][r][c + k];
                m2 += wk * v[2][r][c + k];
                m3 += wk * v[3][r][c + k];
                m4 += wk * v[4][r][c + k];
            }
            float mux = m0, muy = m1;
            float sxx = m2 - mux * mux;
            float syy = m3 - muy * muy;
            float sxy = m4 - mux * muy;
            float cs = (2.0f * sxy + c2) / (sxx + syy + c2);
            float lm = (2.0f * mux * muy + c1) / (mux * mux + muy * muy + c1);
            acc += lm * cs;
        }
    }

    // wave(64) shuffle reduction
    for (int off = 32; off > 0; off >>= 1)
        acc += __shfl_down(acc, off, 64);

    int wave = t >> 6;
    if ((t & 63) == 0) wsum[wave] = acc;
    __syncthreads();

    if (t == 0) {
        float s = 0.0f;
#pragma unroll
        for (int i = 0; i < NTHREADS / 64; i++) s += wsum[i];
        atomicAdd(out, s * (1.0f / (float)TOTAL_OUT));
    }
}

extern "C" void kernel_launch(void* const* d_in, const int* in_sizes, int n_in,
                              void* d_out, int out_size, void* d_ws, size_t ws_size,
                              hipStream_t stream)
{
    const float* x   = (const float*)d_in[0];
    const float* y   = (const float*)d_in[1];
    const float* win = (const float*)d_in[2];
    float* out = (float*)d_out;

    zero_out_kernel<<<1, 1, 0, stream>>>(out);

    dim3 grid((OW + TW - 1) / TW, (OH + TH - 1) / TH, NPLANES);
    ssim_kernel<<<grid, NTHREADS, 0, stream>>>(x, y, win, out);
}

// Round 2
// 192.149 us; speedup vs baseline: 1.4060x; 1.4060x over previous
//
#include <hip/hip_runtime.h>
#include <math.h>

// Problem constants
#define KS    11
#define H     512
#define W     512
#define OH    502
#define OW    502
#define NPLANES 48
#define TOTAL_OUT (NPLANES * OH * OW)   // 12,096,192

// Tiling: wide, short tiles. Tile 0: output cols 0..245 (reads input cols 0..255)
//         Tile 1: output cols 246..501 (reads input cols 246..511)
#define TH      8                 // output rows per block
#define IROWS   (TH + KS - 1)     // 18 input rows per block
#define LVW     267               // LDS row stride: max 266 cols + 1 pad (odd -> 2-way banks, free)
#define NTHREADS 256

__global__ void zero_out_kernel(float* out) { out[0] = 0.0f; }

__global__ __launch_bounds__(NTHREADS) void ssim_kernel(
    const float* __restrict__ x,
    const float* __restrict__ y,
    const float* __restrict__ win,
    float* __restrict__ out)
{
    // 5 vertically-convolved signals: mu_x, mu_y, xx, yy, xy
    __shared__ float v[5][TH][LVW];     // 42.7 KB -> 3 blocks/CU
    __shared__ float w1s[KS];
    __shared__ float wsum[NTHREADS / 64];

    const int t     = threadIdx.x;
    const int bx    = blockIdx.x;              // 0 or 1
    const int x0    = bx * 246;                // col base (input & output)
    const int gy0   = blockIdx.y * TH;         // output row base
    const int plane = blockIdx.z;
    const int IWx   = bx ? 266 : 256;          // input cols this tile
    const int TWx   = bx ? 256 : 246;          // output cols this tile

    const float* __restrict__ xp = x + (size_t)plane * (H * W);
    const float* __restrict__ yp = y + (size_t)plane * (H * W);

    // Separable taps: window = outer(g,g) => g[i] = sqrt(win[i][i])
    if (t < KS) w1s[t] = sqrtf(win[t * KS + t]);
    __syncthreads();

    float w[KS];
#pragma unroll
    for (int k = 0; k < KS; k++) w[k] = w1s[k];

    // ---- Stage 1: vertical 11-tap conv, direct from global, regs -> LDS ----
    // Thread owns column(s); scatter each input row into the <=8 output rows it feeds.
    for (int cc = t; cc < IWx; cc += NTHREADS) {
        const int gx = x0 + cc;   // always < 512 by construction
        float a0[TH], a1[TH], a2[TH], a3[TH], a4[TH];
#pragma unroll
        for (int r = 0; r < TH; r++) { a0[r] = 0.f; a1[r] = 0.f; a2[r] = 0.f; a3[r] = 0.f; a4[r] = 0.f; }

#pragma unroll
        for (int j = 0; j < IROWS; j++) {
            const int gy = gy0 + j;
            float xv = 0.f, yv = 0.f;
            if (gy < H) {                       // uniform branch
                xv = xp[gy * W + gx];
                yv = yp[gy * W + gx];
            }
            const float xx = xv * xv;
            const float yy = yv * yv;
            const float xy = xv * yv;
#pragma unroll
            for (int r = 0; r < TH; r++) {
                if (j - r >= 0 && j - r < KS) { // constant-folds after unroll
                    const float wk = w[j - r];
                    a0[r] += wk * xv;
                    a1[r] += wk * yv;
                    a2[r] += wk * xx;
                    a3[r] += wk * yy;
                    a4[r] += wk * xy;
                }
            }
        }
#pragma unroll
        for (int r = 0; r < TH; r++) {
            v[0][r][cc] = a0[r];
            v[1][r][cc] = a1[r];
            v[2][r][cc] = a2[r];
            v[3][r][cc] = a3[r];
            v[4][r][cc] = a4[r];
        }
    }
    __syncthreads();

    // ---- Stage 2: horizontal 11-tap conv over an 8-pixel run + SSIM ----
    const int r  = t & 7;            // row within tile
    const int c0 = (t >> 3) << 3;    // run start col: 0..248 (2-way banks w/ stride 267)

    float mu[5][TH];                 // 40 accumulator regs
#pragma unroll
    for (int s = 0; s < 5; s++) {
        const float* __restrict__ vrow = &v[s][r][c0];
        float vs[IROWS];
#pragma unroll
        for (int j = 0; j < IROWS; j++) vs[j] = vrow[j];
#pragma unroll
        for (int p = 0; p < TH; p++) {
            float m = 0.f;
#pragma unroll
            for (int k = 0; k < KS; k++) m += w[k] * vs[p + k];
            mu[s][p] = m;
        }
    }

    const float c1 = 1e-4f;   // (0.01)^2
    const float c2 = 9e-4f;   // (0.03)^2
    const int grow = gy0 + r;
    float acc = 0.f;
#pragma unroll
    for (int p = 0; p < TH; p++) {
        if ((c0 + p) < TWx && grow < OH) {
            const float mux = mu[0][p], muy = mu[1][p];
            const float sxx = mu[2][p] - mux * mux;
            const float syy = mu[3][p] - muy * muy;
            const float sxy = mu[4][p] - mux * muy;
            const float num = (2.f * sxy + c2) * (2.f * mux * muy + c1);
            const float den = (sxx + syy + c2) * (mux * mux + muy * muy + c1);
            acc += num * __builtin_amdgcn_rcpf(den);
        }
    }

    // ---- Reduction: wave shuffle -> cross-wave LDS -> one atomic/block ----
#pragma unroll
    for (int off = 32; off > 0; off >>= 1)
        acc += __shfl_down(acc, off, 64);

    if ((t & 63) == 0) wsum[t >> 6] = acc;
    __syncthreads();
    if (t == 0) {
        float s = 0.f;
#pragma unroll
        for (int i = 0; i < NTHREADS / 64; i++) s += wsum[i];
        atomicAdd(out, s * (1.0f / (float)TOTAL_OUT));
    }
}

extern "C" void kernel_launch(void* const* d_in, const int* in_sizes, int n_in,
                              void* d_out, int out_size, void* d_ws, size_t ws_size,
                              hipStream_t stream)
{
    const float* x   = (const float*)d_in[0];
    const float* y   = (const float*)d_in[1];
    const float* win = (const float*)d_in[2];
    float* out = (float*)d_out;

    zero_out_kernel<<<1, 1, 0, stream>>>(out);

    dim3 grid(2, (OH + TH - 1) / TH, NPLANES);   // (2, 63, 48) = 6048 blocks
    ssim_kernel<<<grid, NTHREADS, 0, stream>>>(x, y, win, out);
}